// Round 1
// baseline (119.181 us; speedup 1.0000x reference)
//
#include <hip/hip_runtime.h>
#include <hip/hip_bf16.h>

#define TABN 4096
#define NF 16

// ---------------------------------------------------------------------------
// Builder: tabulate g(ds_clipped) = b + sum_f w_s[f]*sin(ds/1024*2^f)
//                                        + w_c[f]*cos(ds/1024*2^f)
// over ds_clipped in [-4, 4], TABN+1 samples, computed in double.
// Runs every launch (d_ws is re-poisoned before each timed call).
// ---------------------------------------------------------------------------
__global__ void rsb_build_table(const float* __restrict__ w,
                                const float* __restrict__ bptr,
                                float* __restrict__ tab) {
  int k = blockIdx.x * blockDim.x + threadIdx.x;
  if (k > TABN) return;
  double dsc = -4.0 + 8.0 * (double)k / (double)TABN;  // clipped ds value
  double x = dsc / 1024.0;                             // post SCALE_DIVISOR
  double acc = (double)bptr[0];
#pragma unroll
  for (int f = 0; f < NF; ++f) {
    double a = x * (double)(1 << f);
    acc += (double)w[f] * sin(a) + (double)w[NF + f] * cos(a);
  }
  tab[k] = (float)acc;
}

// ---------------------------------------------------------------------------
// Main kernel: one (b, 32-row, 256-col) tile per block of 256 threads.
// Each thread: 4 consecutive j columns (float4 I/O), loops 8 i rows.
// ---------------------------------------------------------------------------
__device__ __forceinline__ float rsb_elem(const float* __restrict__ tab_s,
                                          float4 pi, float4 pj, bool valid) {
  float dx = pi.x - pj.x;
  float dy = pi.y - pj.y;
  float dz = pi.z - pj.z;
  float dt = pi.w - pj.w;
  // Match numpy f32 op order exactly: ((dt*dt - dx*dx) - dy*dy) - dz*dz,
  // no FMA contraction (near-zero cancellation must track the reference).
  float ds2 = __fsub_rn(
      __fsub_rn(__fsub_rn(__fmul_rn(dt, dt), __fmul_rn(dx, dx)),
                __fmul_rn(dy, dy)),
      __fmul_rn(dz, dz));
  float rr = sqrtf(fabsf(ds2) + 1e-12f);
  float dsv = (ds2 > 0.f) ? rr : ((ds2 < 0.f) ? -rr : 0.f);  // sign(0)=0
  dsv = fminf(4.f, fmaxf(-4.f, dsv));                        // clip
  float t = (dsv + 4.f) * (float)(TABN / 8);                 // [0, TABN]
  int it = (int)t;
  it = max(0, min(it, TABN - 1));
  float frac = t - (float)it;
  float v0 = tab_s[it];
  float v1 = tab_s[it + 1];
  float g = fmaf(frac, v1 - v0, v0);
  return valid ? g : 0.f;
}

__global__ __launch_bounds__(256) void rsb_main(
    const float* __restrict__ pos, const int* __restrict__ mask,
    const float* __restrict__ tab, float* __restrict__ out, int S) {
  __shared__ float4 tab4_s[TABN / 4 + 1];
  __shared__ float4 pi_s[32];
  __shared__ int mi_s[32];
  float* tab_s = (float*)tab4_s;

  const int tid = threadIdx.x;
  const int b = blockIdx.z;
  const int ibase = blockIdx.y * 32;
  const int jbase = blockIdx.x * 256;

  // Stage table (4096 floats, coalesced float4) + 32 i-rows + i-mask.
  {
    const float4* t4 = (const float4*)tab;
#pragma unroll
    for (int r = 0; r < 4; ++r) tab4_s[r * 256 + tid] = t4[r * 256 + tid];
    if (tid == 0) tab_s[TABN] = tab[TABN];  // guard entry
    if (tid < 32 && (ibase + tid) < S) {
      pi_s[tid] = ((const float4*)pos)[(size_t)b * S + ibase + tid];
      mi_s[tid] = mask[(size_t)b * S + ibase + tid];
    }
  }
  __syncthreads();

  const int tx = tid & 63;
  const int ty = tid >> 6;
  const int j4 = jbase + tx * 4;
  if (j4 >= S) return;

  const float4* pjp = (const float4*)pos + (size_t)b * S + j4;
  float4 pj0 = pjp[0];
  float4 pj1 = pjp[1];
  float4 pj2 = pjp[2];
  float4 pj3 = pjp[3];
  int4 mj = *(const int4*)(mask + (size_t)b * S + j4);

#pragma unroll
  for (int r = 0; r < 8; ++r) {
    int irow = r * 4 + ty;
    int i = ibase + irow;
    if (i >= S) break;  // uniform per wave (ty uniform within wave)
    float4 pi = pi_s[irow];
    int mi = mi_s[irow];
    float4 o;
    o.x = rsb_elem(tab_s, pi, pj0, (mi != 0) && (mj.x != 0));
    o.y = rsb_elem(tab_s, pi, pj1, (mi != 0) && (mj.y != 0));
    o.z = rsb_elem(tab_s, pi, pj2, (mi != 0) && (mj.z != 0));
    o.w = rsb_elem(tab_s, pi, pj3, (mi != 0) && (mj.w != 0));
    *(float4*)(out + ((size_t)b * S + i) * S + j4) = o;
  }
}

// ---------------------------------------------------------------------------
extern "C" void kernel_launch(void* const* d_in, const int* in_sizes, int n_in,
                              void* d_out, int out_size, void* d_ws,
                              size_t ws_size, hipStream_t stream) {
  const float* pos = (const float*)d_in[0];   // (B,S,4) f32
  const int* mask = (const int*)d_in[1];      // (B,S) int
  const float* w = (const float*)d_in[2];     // (1,32) f32
  const float* bb = (const float*)d_in[3];    // (1,) f32
  float* out = (float*)d_out;                 // (B,S,S) f32

  const int BS = in_sizes[1];                 // B*S
  const int S = (int)((long long)out_size / BS);
  const int B = BS / S;

  float* tab = (float*)d_ws;  // (TABN+1) floats of scratch

  rsb_build_table<<<(TABN + 1 + 255) / 256, 256, 0, stream>>>(w, bb, tab);

  dim3 grid((S + 255) / 256, (S + 31) / 32, B);
  rsb_main<<<grid, 256, 0, stream>>>(pos, mask, tab, out, S);
}

// Round 2
// 97.465 us; speedup vs baseline: 1.2228x; 1.2228x over previous
//
#include <hip/hip_runtime.h>
#include <hip/hip_bf16.h>

#define TABN 4096
#define NF 16

// ---------------------------------------------------------------------------
// Builder: tabulate g(ds_clipped) = b + sum_f w_s[f]*sin(ds/1024*2^f)
//                                        + w_c[f]*cos(ds/1024*2^f)
// over ds_clipped in [-4, 4], TABN+1 samples.
// f32 + libm sincosf: matches the reference's f32 trig, and avoids the
// 50 µs f64 software-libm path (round-1 profile: builder was half the time).
// Runs every launch (d_ws is re-poisoned before each timed call).
// ---------------------------------------------------------------------------
__global__ void rsb_build_table(const float* __restrict__ w,
                                const float* __restrict__ bptr,
                                float* __restrict__ tab) {
  int k = blockIdx.x * blockDim.x + threadIdx.x;
  if (k > TABN) return;
  float dsc = -4.f + 8.f * (float)k / (float)TABN;  // clipped ds value
  float x = dsc * (1.f / 1024.f);                   // post SCALE_DIVISOR (exact)
  float acc = bptr[0];
#pragma unroll
  for (int f = 0; f < NF; ++f) {
    float a = x * (float)(1 << f);  // pow2 scale: exact
    float s, c;
    sincosf(a, &s, &c);             // ~1 ulp, full range reduction (|a|<=128)
    acc = fmaf(w[f], s, acc);
    acc = fmaf(w[NF + f], c, acc);
  }
  tab[k] = acc;
}

// ---------------------------------------------------------------------------
// Main kernel: one (b, 32-row, 256-col) tile per block of 256 threads.
// Each thread: 4 consecutive j columns (float4 I/O), loops 8 i rows.
// ---------------------------------------------------------------------------
__device__ __forceinline__ float rsb_elem(const float* __restrict__ tab_s,
                                          float4 pi, float4 pj, bool valid) {
  float dx = pi.x - pj.x;
  float dy = pi.y - pj.y;
  float dz = pi.z - pj.z;
  float dt = pi.w - pj.w;
  // Match numpy f32 op order exactly: ((dt*dt - dx*dx) - dy*dy) - dz*dz,
  // no FMA contraction (near-zero cancellation must track the reference).
  float ds2 = __fsub_rn(
      __fsub_rn(__fsub_rn(__fmul_rn(dt, dt), __fmul_rn(dx, dx)),
                __fmul_rn(dy, dy)),
      __fmul_rn(dz, dz));
  float rr = sqrtf(fabsf(ds2) + 1e-12f);
  float dsv = (ds2 > 0.f) ? rr : ((ds2 < 0.f) ? -rr : 0.f);  // sign(0)=0
  dsv = fminf(4.f, fmaxf(-4.f, dsv));                        // clip
  float t = (dsv + 4.f) * (float)(TABN / 8);                 // [0, TABN]
  int it = (int)t;
  it = max(0, min(it, TABN - 1));
  float frac = t - (float)it;
  float v0 = tab_s[it];
  float v1 = tab_s[it + 1];
  float g = fmaf(frac, v1 - v0, v0);
  return valid ? g : 0.f;
}

__global__ __launch_bounds__(256) void rsb_main(
    const float* __restrict__ pos, const int* __restrict__ mask,
    const float* __restrict__ tab, float* __restrict__ out, int S) {
  __shared__ float4 tab4_s[TABN / 4 + 1];
  __shared__ float4 pi_s[32];
  __shared__ int mi_s[32];
  float* tab_s = (float*)tab4_s;

  const int tid = threadIdx.x;
  const int b = blockIdx.z;
  const int ibase = blockIdx.y * 32;
  const int jbase = blockIdx.x * 256;

  // Stage table (4096 floats, coalesced float4) + 32 i-rows + i-mask.
  {
    const float4* t4 = (const float4*)tab;
#pragma unroll
    for (int r = 0; r < 4; ++r) tab4_s[r * 256 + tid] = t4[r * 256 + tid];
    if (tid == 0) tab_s[TABN] = tab[TABN];  // guard entry
    if (tid < 32 && (ibase + tid) < S) {
      pi_s[tid] = ((const float4*)pos)[(size_t)b * S + ibase + tid];
      mi_s[tid] = mask[(size_t)b * S + ibase + tid];
    }
  }
  __syncthreads();

  const int tx = tid & 63;
  const int ty = tid >> 6;
  const int j4 = jbase + tx * 4;
  if (j4 >= S) return;

  const float4* pjp = (const float4*)pos + (size_t)b * S + j4;
  float4 pj0 = pjp[0];
  float4 pj1 = pjp[1];
  float4 pj2 = pjp[2];
  float4 pj3 = pjp[3];
  int4 mj = *(const int4*)(mask + (size_t)b * S + j4);

#pragma unroll
  for (int r = 0; r < 8; ++r) {
    int irow = r * 4 + ty;
    int i = ibase + irow;
    if (i >= S) break;  // uniform per wave (ty uniform within wave)
    float4 pi = pi_s[irow];
    int mi = mi_s[irow];
    float4 o;
    o.x = rsb_elem(tab_s, pi, pj0, (mi != 0) && (mj.x != 0));
    o.y = rsb_elem(tab_s, pi, pj1, (mi != 0) && (mj.y != 0));
    o.z = rsb_elem(tab_s, pi, pj2, (mi != 0) && (mj.z != 0));
    o.w = rsb_elem(tab_s, pi, pj3, (mi != 0) && (mj.w != 0));
    *(float4*)(out + ((size_t)b * S + i) * S + j4) = o;
  }
}

// ---------------------------------------------------------------------------
extern "C" void kernel_launch(void* const* d_in, const int* in_sizes, int n_in,
                              void* d_out, int out_size, void* d_ws,
                              size_t ws_size, hipStream_t stream) {
  const float* pos = (const float*)d_in[0];   // (B,S,4) f32
  const int* mask = (const int*)d_in[1];      // (B,S) int
  const float* w = (const float*)d_in[2];     // (1,32) f32
  const float* bb = (const float*)d_in[3];    // (1,) f32
  float* out = (float*)d_out;                 // (B,S,S) f32

  const int BS = in_sizes[1];                 // B*S
  const int S = (int)((long long)out_size / BS);
  const int B = BS / S;

  float* tab = (float*)d_ws;  // (TABN+1) floats of scratch

  rsb_build_table<<<(TABN + 1 + 255) / 256, 256, 0, stream>>>(w, bb, tab);

  dim3 grid((S + 255) / 256, (S + 31) / 32, B);
  rsb_main<<<grid, 256, 0, stream>>>(pos, mask, tab, out, S);
}

// Round 4
// 95.431 us; speedup vs baseline: 1.2489x; 1.0213x over previous
//
#include <hip/hip_runtime.h>
#include <hip/hip_bf16.h>

#define TABN 4096
#define NF 16

// ---------------------------------------------------------------------------
// Table: g(ds_clipped) = b + sum_f ws[f]*sin(ds/1024*2^f) + wc[f]*cos(...)
// over ds in [-4,4], TABN intervals. Entry k = {g(k), g(k+1)-g(k)} (base,slope).
//
// sincosf only for f=0..7 (|a| <= 0.5 rad: libm fast path, ~1 ulp). f=8..15
// via double-angle recurrence (3 FMA/step): error amplification 2^8 * 1ulp
// ~= 2e-5 per term -> <=1e-4 bias error, negligible vs 0.0317 threshold.
// Avoids libm's large-arg range-reduction latency entirely.
// ---------------------------------------------------------------------------
__device__ __forceinline__ float rsb_eval(int k, const float* __restrict__ w,
                                          float bias) {
  // dsc = -4 + k/512 (exact in f32); x = dsc/1024 (exact).
  float x = (-4.f + (float)k * (1.f / 512.f)) * (1.f / 1024.f);
  float acc = bias;
  float s7 = 0.f, c7 = 1.f;
#pragma unroll
  for (int f = 0; f < 8; ++f) {
    float a = x * (float)(1 << f);  // pow2 scale: exact
    float s, c;
    sincosf(a, &s, &c);             // |a| <= 0.5 rad: fast path
    acc = fmaf(w[f], s, acc);
    acc = fmaf(w[NF + f], c, acc);
    if (f == 7) { s7 = s; c7 = c; }
  }
  float ss = s7, cc = c7;
#pragma unroll
  for (int f = 8; f < NF; ++f) {
    float ns = 2.f * ss * cc;             // sin(2a)
    float nc = fmaf(cc, cc, -(ss * ss));  // cos(2a) = c^2 - s^2
    ss = ns;
    cc = nc;
    acc = fmaf(w[f], ss, acc);
    acc = fmaf(w[NF + f], cc, acc);
  }
  return acc;
}

__global__ void rsb_build_table(const float* __restrict__ w,
                                const float* __restrict__ bptr,
                                float2* __restrict__ tab) {
  int k = blockIdx.x * blockDim.x + threadIdx.x;
  if (k >= TABN) return;
  float bias = bptr[0];
  float g0 = rsb_eval(k, w, bias);
  float g1 = rsb_eval(k + 1, w, bias);
  tab[k] = make_float2(g0, g1 - g0);
}

// ---------------------------------------------------------------------------
// Main: one (b, 32-row, 512-col) tile per 512-thread block.
// Each thread: 4 consecutive j (float4 I/O), 8 i-rows.
// LDS: 32KB {base,slope} table + 32 i-rows. 4 blocks/CU -> 32 waves/CU.
// ---------------------------------------------------------------------------
__device__ __forceinline__ float rsb_elem(const float2* __restrict__ tab_s,
                                          float4 pi, float4 pj, bool valid) {
  float dx = pi.x - pj.x;
  float dy = pi.y - pj.y;
  float dz = pi.z - pj.z;
  float dt = pi.w - pj.w;
  // Exact numpy f32 op order: ((dt*dt - dx*dx) - dy*dy) - dz*dz, no FMA
  // contraction (light-cone cancellation must track the reference).
  float ds2 = __fsub_rn(
      __fsub_rn(__fsub_rn(__fmul_rn(dt, dt), __fmul_rn(dx, dx)),
                __fmul_rn(dy, dy)),
      __fmul_rn(dz, dz));
  float rr = sqrtf(fabsf(ds2) + 1e-12f);
  float dsv = __builtin_copysignf(rr, ds2);       // sign(0) diff: ~1e-6, ok
  dsv = __builtin_amdgcn_fmed3f(dsv, -4.f, 4.f);  // clip
  float t = fmaf(dsv, (float)(TABN / 8), (float)(TABN / 2));  // [0, TABN]
  int it = (int)t;
  it = min(it, TABN - 1);
  float frac = t - (float)it;                     // ==1.0 when clamped
  float2 bs = tab_s[it];                          // single ds_read_b64
  float g = fmaf(frac, bs.y, bs.x);
  return valid ? g : 0.f;
}

__global__ __launch_bounds__(512, 8) void rsb_main(
    const float* __restrict__ pos, const int* __restrict__ mask,
    const float2* __restrict__ tab, float* __restrict__ out, int S) {
  __shared__ float4 tab4_s[TABN / 2];  // 32 KB: TABN float2 as float4 pairs
  __shared__ float4 pi_s[32];
  __shared__ int mi_s[32];
  const float2* tab_s = (const float2*)tab4_s;

  const int tid = threadIdx.x;
  const int b = blockIdx.z;
  const int ibase = blockIdx.y * 32;
  const int jbase = blockIdx.x * 512;

  {
    const float4* t4 = (const float4*)tab;
#pragma unroll
    for (int r = 0; r < 4; ++r) tab4_s[r * 512 + tid] = t4[r * 512 + tid];
    if (tid < 32 && (ibase + tid) < S) {
      pi_s[tid] = ((const float4*)pos)[(size_t)b * S + ibase + tid];
      mi_s[tid] = mask[(size_t)b * S + ibase + tid];
    }
  }
  __syncthreads();

  const int tx = tid & 127;
  const int ty = tid >> 7;
  const int j4 = jbase + tx * 4;
  if (j4 >= S) return;

  const float4* pjp = (const float4*)pos + (size_t)b * S + j4;
  float4 pj0 = pjp[0];
  float4 pj1 = pjp[1];
  float4 pj2 = pjp[2];
  float4 pj3 = pjp[3];
  int4 mj = *(const int4*)(mask + (size_t)b * S + j4);

#pragma unroll
  for (int r = 0; r < 8; ++r) {
    int irow = r * 4 + ty;
    int i = ibase + irow;
    if (i >= S) break;  // uniform per wave (ty uniform within wave)
    float4 pi = pi_s[irow];
    bool mi = (mi_s[irow] != 0);
    float4 o;
    o.x = rsb_elem(tab_s, pi, pj0, mi && (mj.x != 0));
    o.y = rsb_elem(tab_s, pi, pj1, mi && (mj.y != 0));
    o.z = rsb_elem(tab_s, pi, pj2, mi && (mj.z != 0));
    o.w = rsb_elem(tab_s, pi, pj3, mi && (mj.w != 0));
    *(float4*)(out + ((size_t)b * S + i) * S + j4) = o;
  }
}

// ---------------------------------------------------------------------------
extern "C" void kernel_launch(void* const* d_in, const int* in_sizes, int n_in,
                              void* d_out, int out_size, void* d_ws,
                              size_t ws_size, hipStream_t stream) {
  const float* pos = (const float*)d_in[0];   // (B,S,4) f32
  const int* mask = (const int*)d_in[1];      // (B,S) int
  const float* w = (const float*)d_in[2];     // (1,32) f32
  const float* bb = (const float*)d_in[3];    // (1,) f32
  float* out = (float*)d_out;                 // (B,S,S) f32

  const int BS = in_sizes[1];                 // B*S
  const int S = (int)((long long)out_size / BS);
  const int B = BS / S;

  float2* tab = (float2*)d_ws;  // TABN float2 = 32 KB scratch

  rsb_build_table<<<(TABN + 255) / 256, 256, 0, stream>>>(w, bb, tab);

  dim3 grid((S + 511) / 512, (S + 31) / 32, B);
  rsb_main<<<grid, 512, 0, stream>>>(pos, mask, tab, out, S);
}